// Round 1
// baseline (20377.361 us; speedup 1.0000x reference)
//
#include <hip/hip_runtime.h>
#include <stdint.h>
#include <stddef.h>

// PowerLawLayer RNN, MI355X persistent-kernel, R5.
//
// R1: 1024-thr wg => 128-VGPR cap, alloc 64 => full weight spill, 39 ms.
// R2: 512-thr wg => alloc 128, demand ~180 => ~50-reg spill = 27 GB FETCH, 44 ms.
// R3: amdgpu_waves_per_eu(2,2) IGNORED (VGPR stayed 128, same spill bytes).
// R4: demand under the 128 cap: wg = (16 j's) x (full k=768) x (8 batches);
//   256 wgs = 32 slices x 8 batch groups; group g <-> XCD g (bid&7).
//   19.7 ms, but VALUBusy 11.6% / HBM 1.3% => latency-bound, ~19.2 us/step
//   vs 0.96 us/step FMA floor.
// R5: the R4 barrier was 256 atomic fetch_adds/step into ONE 128B line
//   (ctr[0..7] contiguous) + an agent-ACQUIRE load per spin iteration
//   (per-iteration cache invalidate on a chip with non-coherent XCD L2s).
//   LLC serializes same-line RMWs at ~50-100ns each => ~13-25 us/step,
//   matching the measurement. Replace with per-WG flag STORES:
//   flags[g*32+s] = t+1 (release, no RMW), one 128B line per group;
//   wave 0 polls all 32 peer flags with one 32-lane RELAXED load +
//   __all ballot, then a single ACQUIRE load after success.
//
// Workspace: hbuf[2][64][512] f32 ping-pong + flags[8][32] u32 = 263,168 B.

#define Hh   512
#define Tt   1024
#define Bb   64
#define II   256
#define EPSc 0.001f
#define PV   0.2f
#define NPEER 32

__global__ __launch_bounds__(1024) void plr_init(float* hbuf, unsigned* flags) {
  int idx = blockIdx.x * blockDim.x + threadIdx.x;
  if (idx < Bb * Hh) hbuf[idx] = 0.0f;        // h(0) = 0 in buffer 0
  if (idx < 8 * NPEER) flags[idx] = 0u;       // per-WG step flags
}

__global__ __launch_bounds__(512, 3)  // min 3 waves/EU -> ~170 VGPR cap;
void plr_main(                        // demand ~120 -> no spill either way
    const float* __restrict__ x,    // [B, T, I]
    const float* __restrict__ Wih,  // [3H, I]
    const float* __restrict__ Whh,  // [3H, H]
    const float* __restrict__ bias, // [3H]
    float* __restrict__ out,        // [B,T,H] ++ h_f ++ c_f ++ k_f
    float* hbuf,                    // [2][B][H]
    unsigned* flags)                // [8][32] — one 128B line per group
{
  __shared__ float h_tile[8 * Hh];        // [bl][k]      16 KB
  __shared__ float x_tile[2 * 8 * II];    // [buf][bl][k] 16 KB
  __shared__ float part[3264];            // ((gi*8+bl)*8+w)*17 + jj  12.8 KB

  const int tid = threadIdx.x;
  const int w   = tid >> 6;          // wave 0..7
  const int l   = tid & 63;
  const int jj  = l & 15;            // hidden offset within slice
  const int kl  = (l >> 4) & 3;      // k sub-chunk within wave
  const int kc  = (w << 2) | kl;     // k-chunk 0..31
  const int bid = blockIdx.x;
  const int g   = bid & 7;           // batch group == XCD (round-robin)
  const int s   = bid >> 3;          // hidden slice 0..31
  const int j0  = s * 16;
  const int b0  = g * 8;

  // ---- one-time: weights into registers (72 floats/thread) ------------
  float whh[3][16];
  float wih[3][8];
#pragma unroll
  for (int gi = 0; gi < 3; ++gi) {
    const int row = gi * Hh + j0 + jj;
    const float4* ph = (const float4*)(Whh + (size_t)row * Hh + kc * 16);
#pragma unroll
    for (int i = 0; i < 4; ++i) {
      float4 v = ph[i];
      whh[gi][4*i+0] = v.x; whh[gi][4*i+1] = v.y;
      whh[gi][4*i+2] = v.z; whh[gi][4*i+3] = v.w;
    }
    const float4* pi = (const float4*)(Wih + (size_t)row * II + kc * 8);
#pragma unroll
    for (int i = 0; i < 2; ++i) {
      float4 v = pi[i];
      wih[gi][4*i+0] = v.x; wih[gi][4*i+1] = v.y;
      wih[gi][4*i+2] = v.z; wih[gi][4*i+3] = v.w;
    }
  }

  // ---- updater state (threads 0..127: br = tid>>4, jr = tid&15) -------
  float c_st = 0.0f, k_st = -1.0f;
  float bia0 = 0.f, bia1 = 0.f, bia2 = 0.f;
  if (tid < 128) {
    const int jr = tid & 15;
    bia0 = bias[0 * Hh + j0 + jr];
    bia1 = bias[1 * Hh + j0 + jr];
    bia2 = bias[2 * Hh + j0 + jr];
  }

  // ---- prologue: stage x(0) -------------------------------------------
  {
    const int bl = tid >> 6, k4 = (tid & 63) * 4;
    *(float4*)(x_tile + bl * II + k4) =
        *(const float4*)(x + ((size_t)(b0 + bl) * Tt + 0) * II + k4);
  }

  bool broken = false;  // bounded-spin escape (never taken when co-resident)

  for (int t = 0; t < Tt; ++t) {
    // ---- stage h(t) from LLC (agent atomics; peers may be remote) ------
    {
      const float* hb = hbuf + (size_t)(t & 1) * Bb * Hh + (size_t)b0 * Hh;
#pragma unroll
      for (int i = 0; i < 8; ++i)
        h_tile[i * Hh + tid] = __hip_atomic_load(
            hb + i * Hh + tid, __ATOMIC_RELAXED, __HIP_MEMORY_SCOPE_AGENT);
    }
    __syncthreads();  // (A) h_tile + x_tile ready

    // ---- gemv: 576 FMA/thread in 2 passes of 4 batches -----------------
    const float* xt = x_tile + (t & 1) * 8 * II;
#pragma unroll
    for (int pass = 0; pass < 2; ++pass) {
      float acc[3][4];
#pragma unroll
      for (int b4 = 0; b4 < 4; ++b4) {
        const int bl = pass * 4 + b4;
        const float4* h4 = (const float4*)(h_tile + bl * Hh) + kc * 4;
        const float4* x4 = (const float4*)(xt + bl * II) + kc * 2;
        float a0 = 0.f, a1 = 0.f, a2 = 0.f;
#pragma unroll
        for (int i = 0; i < 4; ++i) {
          float4 hv = h4[i];
          a0 = fmaf(whh[0][4*i+0], hv.x, a0); a0 = fmaf(whh[0][4*i+1], hv.y, a0);
          a0 = fmaf(whh[0][4*i+2], hv.z, a0); a0 = fmaf(whh[0][4*i+3], hv.w, a0);
          a1 = fmaf(whh[1][4*i+0], hv.x, a1); a1 = fmaf(whh[1][4*i+1], hv.y, a1);
          a1 = fmaf(whh[1][4*i+2], hv.z, a1); a1 = fmaf(whh[1][4*i+3], hv.w, a1);
          a2 = fmaf(whh[2][4*i+0], hv.x, a2); a2 = fmaf(whh[2][4*i+1], hv.y, a2);
          a2 = fmaf(whh[2][4*i+2], hv.z, a2); a2 = fmaf(whh[2][4*i+3], hv.w, a2);
        }
#pragma unroll
        for (int i = 0; i < 2; ++i) {
          float4 xv = x4[i];
          a0 = fmaf(wih[0][4*i+0], xv.x, a0); a0 = fmaf(wih[0][4*i+1], xv.y, a0);
          a0 = fmaf(wih[0][4*i+2], xv.z, a0); a0 = fmaf(wih[0][4*i+3], xv.w, a0);
          a1 = fmaf(wih[1][4*i+0], xv.x, a1); a1 = fmaf(wih[1][4*i+1], xv.y, a1);
          a1 = fmaf(wih[1][4*i+2], xv.z, a1); a1 = fmaf(wih[1][4*i+3], xv.w, a1);
          a2 = fmaf(wih[2][4*i+0], xv.x, a2); a2 = fmaf(wih[2][4*i+1], xv.y, a2);
          a2 = fmaf(wih[2][4*i+2], xv.z, a2); a2 = fmaf(wih[2][4*i+3], xv.w, a2);
        }
        acc[0][b4] = a0; acc[1][b4] = a1; acc[2][b4] = a2;
      }
      // reduce the 4 kl sub-chunks in-register, one masked store per combo
#pragma unroll
      for (int gi = 0; gi < 3; ++gi)
#pragma unroll
        for (int b4 = 0; b4 < 4; ++b4) {
          float v = acc[gi][b4];
          v += __shfl_xor(v, 16, 64);
          v += __shfl_xor(v, 32, 64);
          if (l < 16)
            part[((gi * 8 + pass * 4 + b4) * 8 + w) * 17 + jj] = v;
        }
    }

    // ---- stage x(t+1) during the gap (independent of h exchange) -------
    if (t + 1 < Tt) {
      const int bl = tid >> 6, k4 = (tid & 63) * 4;
      *(float4*)(x_tile + ((t + 1) & 1) * 8 * II + bl * II + k4) =
          *(const float4*)(x + ((size_t)(b0 + bl) * Tt + (t + 1)) * II + k4);
    }
    __syncthreads();  // (B) partials visible

    // ---- reduce + elementwise + h store (threads 0..127) ---------------
    float hn = 0.f, cn = 0.f, kn = 0.f;
    if (tid < 128) {
      const int jr = tid & 15, br = tid >> 4;
      float s0 = bia0, s1 = bia1, s2 = bia2;
#pragma unroll
      for (int ww = 0; ww < 8; ++ww) {
        s0 += part[((0 * 8 + br) * 8 + ww) * 17 + jr];
        s1 += part[((1 * 8 + br) * 8 + ww) * 17 + jr];
        s2 += part[((2 * 8 + br) * 8 + ww) * 17 + jr];
      }
      const float tf = (float)t;
      const float r  = 1.0f / (1.0f + __expf(-s0));
      const float o  = 1.0f / (1.0f + __expf(-s1));
      const float gg = 1.0f - 2.0f / (1.0f + __expf(2.0f * s2));
      kn = r * (tf - EPSc) + (1.0f - r) * k_st;
      const float d  = tf - kn;
      const float f  = __expf(PV * __logf((d + EPSc) / (d + 1.0f)));
      cn = f * c_st + (1.0f - f) * gg;
      hn = o * (1.0f - 2.0f / (1.0f + __expf(2.0f * cn)));
      c_st = cn; k_st = kn;
      __hip_atomic_store(
          hbuf + (size_t)((t + 1) & 1) * Bb * Hh + (size_t)(b0 + br) * Hh +
              j0 + jr,
          hn, __ATOMIC_RELAXED, __HIP_MEMORY_SCOPE_AGENT);
    }
    __syncthreads();  // (C) drains hbuf atomic stores before the signal

    // ---- signal: per-WG flag store (own word; one 128B line per group) --
    if (t < Tt - 1 && tid == 0)
      __hip_atomic_store(flags + g * NPEER + s, (unsigned)(t + 1),
                         __ATOMIC_RELEASE, __HIP_MEMORY_SCOPE_AGENT);

    // ---- out[] store (off the critical path, after the signal) ---------
    if (tid < 128) {
      const int jr = tid & 15, br = tid >> 4;
      const int b = b0 + br, j = j0 + jr;
      out[((size_t)b * Tt + t) * Hh + j] = hn;
      if (t == Tt - 1) {
        const size_t base = (size_t)Bb * Tt * Hh;
        out[base + 0 * Bb * Hh + (size_t)b * Hh + j] = hn;  // h_f
        out[base + 1 * Bb * Hh + (size_t)b * Hh + j] = cn;  // c_f
        out[base + 2 * Bb * Hh + (size_t)b * Hh + j] = kn;  // k_f
      }
    }

    // ---- 32-peer wait: wave 0 polls all 32 flags, relaxed + ballot -----
    if (t < Tt - 1) {
      if (tid < 64 && !broken) {
        const unsigned target = (unsigned)(t + 1);
        const unsigned* fl = flags + g * NPEER + (tid & (NPEER - 1));
        int it = 0;
        for (;;) {
          unsigned v = __hip_atomic_load(fl, __ATOMIC_RELAXED,
                                         __HIP_MEMORY_SCOPE_AGENT);
          if (__all((int)(v >= target))) break;
          __builtin_amdgcn_s_sleep(1);
          if (++it > (1 << 22)) { broken = true; break; }
        }
        // single acquire pairs with the peers' release stores (one
        // invalidate per step instead of one per spin iteration)
        (void)__hip_atomic_load(fl, __ATOMIC_ACQUIRE,
                                __HIP_MEMORY_SCOPE_AGENT);
      }
      __syncthreads();  // (D) all threads ordered behind wave 0's acquire
    }
  }
}

extern "C" void kernel_launch(void* const* d_in, const int* in_sizes, int n_in,
                              void* d_out, int out_size, void* d_ws, size_t ws_size,
                              hipStream_t stream) {
  const float* x    = (const float*)d_in[0];
  const float* Wih  = (const float*)d_in[1];
  const float* Whh  = (const float*)d_in[2];
  const float* bias = (const float*)d_in[3];
  float* out = (float*)d_out;

  float*    hbuf  = (float*)d_ws;                                 // 2*64*512 f32
  unsigned* flags = (unsigned*)((char*)d_ws + 2 * Bb * Hh * sizeof(float));

  plr_init<<<32, 1024, 0, stream>>>(hbuf, flags);
  plr_main<<<256, 512, 0, stream>>>(x, Wih, Whh, bias, out, hbuf, flags);
}